// Round 6
// baseline (252.091 us; speedup 1.0000x reference)
//
#include <hip/hip_runtime.h>
#include <math.h>

// B=8, L=512, H=768, T=9, HEADS=12, d=64
//   Q = hs@Wq + bq ; K = hs@Wk + bk  (M=4096, N=6912, K=768)  -> RoPE -> bf16
//   score[b,i,j,t] = (1/96) * Qr[b*512+i, t*768:+768] . Kr[b*512+j, t*768:+768]
// R5: both GEMMs on a 128x128 BK=64 double-buffered 2-phase engine with
// counted vmcnt(8) (loads stay in flight across barriers), 64KB LDS ->
// 2 blocks/CU for inter-block overlap (m114/m102 mechanism). No sched_barrier,
// no manual lgkmcnt (compiler's own waitcnts handle RAW), no setprio (null @2ph).

typedef __attribute__((ext_vector_type(4))) float f32x4;
typedef __attribute__((ext_vector_type(8))) __bf16 bf16x8;
typedef __attribute__((ext_vector_type(8))) unsigned short ushort8;

#define HH   768
#define NCOL 6912
#define LL   512
#define NT   12      // K-tiles of 64

static __device__ __forceinline__ unsigned short f2bf(float f) {
  unsigned int u = __float_as_uint(f);
  u += 0x7FFFu + ((u >> 16) & 1u);
  return (unsigned short)(u >> 16);
}

static __device__ __forceinline__ void async16(const void* g, void* l) {
  __builtin_amdgcn_global_load_lds(
      (const __attribute__((address_space(1))) unsigned int*)g,
      (__attribute__((address_space(3))) unsigned int*)l, 16, 0, 0);
}

// ---------------- prep kernels ----------------

__global__ void k_conv_hs(const float4* __restrict__ in, ushort8* __restrict__ out) {
  int idx = blockIdx.x * 256 + threadIdx.x;
  float4 a = in[idx * 2], b = in[idx * 2 + 1];
  ushort8 o;
  o[0] = f2bf(a.x); o[1] = f2bf(a.y); o[2] = f2bf(a.z); o[3] = f2bf(a.w);
  o[4] = f2bf(b.x); o[5] = f2bf(b.y); o[6] = f2bf(b.z); o[7] = f2bf(b.w);
  out[idx] = o;
}

// W (768 x 6912) f32 -> Wt (6912 x 768) bf16, rows permuted for in-reg RoPE.
__global__ void k_transpose(const float* __restrict__ Wq, const float* __restrict__ Wk,
                            unsigned short* __restrict__ Wtq, unsigned short* __restrict__ Wtk) {
  __shared__ float tile[32][33];
  const float* W = blockIdx.z ? Wk : Wq;
  unsigned short* Wt = blockIdx.z ? Wtk : Wtq;
  int n0 = blockIdx.x * 32, k0 = blockIdx.y * 32;
  int tx = threadIdx.x, ty0 = threadIdx.y;
#pragma unroll
  for (int j = 0; j < 4; ++j) {
    int ty = ty0 + j * 8;
    tile[ty][tx] = W[(size_t)(k0 + ty) * NCOL + n0 + tx];
  }
  __syncthreads();
#pragma unroll
  for (int j = 0; j < 4; ++j) {
    int ty = ty0 + j * 8;
    int n = n0 + ty;
    int c = n & 63;
    int gc = ((c & 1) << 4) | ((c >> 5) << 5) | ((c & 31) >> 1);
    int np = (n & ~63) | gc;
    Wt[(size_t)np * HH + k0 + tx] = f2bf(tile[tx][ty]);
  }
}

__global__ void k_tables(float2* __restrict__ sc) {
  int idx = blockIdx.x * 256 + threadIdx.x;     // 16384
  int i = idx >> 5, p = idx & 31;
  double ang = (double)i * pow(10000.0, -(double)p / 32.0);
  sc[idx] = make_float2((float)sin(ang), (float)cos(ang));
}

// ---------------- 128x128 BK=64 dbuf counted-vmcnt 2-phase K-loop ----------------
// LDS buf (32KB): A[128 rows][64 K] at byte r*128 + (chunk^(r&7))*16, B same +16K.
// Stage: 8 async16/wave (A j=0..3 rows +j*32, B j=0..3), pre-swizzled global src.
// Per tile: STAGE(nxt,t+1); vmcnt(8); barrier; 16 ds_read + 32 MFMA; barrier.

template <int STR>
static __device__ __forceinline__ void k2_loop(
    const unsigned short* __restrict__ aSrc, const unsigned short* __restrict__ bSrc,
    char* smem, int tid, f32x4 acc[4][4]) {
  const int lane = tid & 63, wid = tid >> 6;
  const int wr = wid >> 1, wc = wid & 1;
  const int ldsW = wid * 1024;
  const int aRdBase = (wr * 64 + (lane & 15)) * 128;
  const int bRdBase = (wc * 64 + (lane & 15)) * 128;
  const int aci0 = ((lane >> 4) ^ (lane & 7)) << 4;
  const int aci1 = ((4 + (lane >> 4)) ^ (lane & 7)) << 4;

  auto stage = [&](int bb, int kt) {
#pragma unroll
    for (int j = 0; j < 4; ++j) {
      async16(aSrc + (size_t)(j * 32) * STR + kt * 64,
              smem + bb * 32768 + j * 4096 + ldsW);
      async16(bSrc + (size_t)(j * 32) * STR + kt * 64,
              smem + bb * 32768 + 16384 + j * 4096 + ldsW);
    }
  };

  stage(0, 0);          // prologue: tile 0 (8 loads in flight)
  int cur = 0;
  for (int t = 0; t < NT; ++t) {
    const int ktn = (t + 1 < NT) ? t + 1 : NT - 1;   // clamped: keeps count exact
    stage(cur ^ 1, ktn);                              // 8 more loads
    asm volatile("s_waitcnt vmcnt(8)" ::: "memory");  // tile t landed; t+1 in flight
    __builtin_amdgcn_s_barrier();

    char* AB = smem + cur * 32768;
    char* BB = AB + 16384;
    bf16x8 Af[4][2], Bf[4][2];
#pragma unroll
    for (int mf = 0; mf < 4; ++mf) {
      Af[mf][0] = *(const bf16x8*)(AB + aRdBase + mf * 2048 + aci0);
      Af[mf][1] = *(const bf16x8*)(AB + aRdBase + mf * 2048 + aci1);
    }
#pragma unroll
    for (int nf = 0; nf < 4; ++nf) {
      Bf[nf][0] = *(const bf16x8*)(BB + bRdBase + nf * 2048 + aci0);
      Bf[nf][1] = *(const bf16x8*)(BB + bRdBase + nf * 2048 + aci1);
    }
#pragma unroll
    for (int kk = 0; kk < 2; ++kk)
#pragma unroll
      for (int mf = 0; mf < 4; ++mf)
#pragma unroll
        for (int nf = 0; nf < 4; ++nf)
          acc[mf][nf] = __builtin_amdgcn_mfma_f32_16x16x32_bf16(
              Af[mf][kk], Bf[nf][kk], acc[mf][nf], 0, 0, 0);
    __builtin_amdgcn_s_barrier();   // all reads of buf[cur] done -> writable next iter
    cur ^= 1;
  }
}

// ---------------- GEMM1: projection + bias + RoPE -> bf16 ----------------

__global__ __launch_bounds__(256) void k2_rope(
    const unsigned short* __restrict__ hsb,
    const unsigned short* __restrict__ Wtq, const unsigned short* __restrict__ Wtk,
    const float* __restrict__ bq, const float* __restrict__ bk,
    const float2* __restrict__ sc,
    unsigned short* __restrict__ Qr, unsigned short* __restrict__ Kr) {
  __shared__ __align__(16) char smem[65536];
  const int bid = blockIdx.x;                 // 3456 = 54n * 32m * 2z
  const int swz = (bid & 7) * 432 + (bid >> 3);
  const int ntile = swz % 54;
  const int rest = swz / 54;
  const int mtile = rest & 31, zz = rest >> 5;
  const unsigned short* Wt = zz ? Wtk : Wtq;
  const float* bias = zz ? bk : bq;
  unsigned short* outp = zz ? Kr : Qr;
  const int m0 = mtile * 128, n0 = ntile * 128;
  const int tid = threadIdx.x;

  const int row_in = tid >> 3;                // 0..31
  const int ci_u = (tid & 7) ^ (row_in & 7);  // pre-swizzled chunk
  const unsigned short* aSrc = hsb + (size_t)(m0 + row_in) * HH + ci_u * 8;
  const unsigned short* bSrc = Wt + (size_t)(n0 + row_in) * HH + ci_u * 8;

  f32x4 acc[4][4] = {};
  k2_loop<HH>(aSrc, bSrc, smem, tid, acc);

  const int lane = tid & 63, wid = tid >> 6;
  const int wr = wid >> 1, wc = wid & 1;
  const int cA = n0 + wc * 64;
  const int e0 = lane & 15, e1 = 16 + e0;
  const float b1a = bias[cA + 2 * e0], b2a = bias[cA + 2 * e0 + 1];
  const float b1b = bias[cA + 2 * e1], b2b = bias[cA + 2 * e1 + 1];

#pragma unroll
  for (int mf = 0; mf < 4; ++mf) {
    const int rbase = m0 + wr * 64 + mf * 16 + (lane >> 4) * 4;
#pragma unroll
    for (int q = 0; q < 4; ++q) {
      const int grow = rbase + q;
      const int i = grow & (LL - 1);
      float2 s0 = sc[i * 32 + e0];
      float2 s1 = sc[i * 32 + e1];
      float x1 = acc[mf][0][q] + b1a, x2 = acc[mf][1][q] + b2a;
      float y1 = acc[mf][2][q] + b1b, y2 = acc[mf][3][q] + b2b;
      size_t ro = (size_t)grow * NCOL + cA;
      outp[ro + e0]      = f2bf(x1 * s0.y - x2 * s0.x);
      outp[ro + e0 + 32] = f2bf(x2 * s0.y + x1 * s0.x);
      outp[ro + e1]      = f2bf(y1 * s1.y - y2 * s1.x);
      outp[ro + e1 + 32] = f2bf(y2 * s1.y + y1 * s1.x);
    }
  }
}

// ---------------- GEMM2: score ----------------

__global__ __launch_bounds__(256) void k2_score(
    const unsigned short* __restrict__ Qr, const unsigned short* __restrict__ Kr,
    float* __restrict__ out) {
  __shared__ __align__(16) char smem[65536];
  const int bid = blockIdx.x;                 // 1152 = 9t * 4jt * 4it * 8b
  const int swz = (bid & 7) * 144 + (bid >> 3);
  const int t = swz % 9;
  const int r2 = swz / 9;
  const int jt = r2 & 3, it = (r2 >> 2) & 3, b = r2 >> 4;
  const int tid = threadIdx.x;

  const int row_in = tid >> 3;
  const int ci_u = (tid & 7) ^ (row_in & 7);
  const unsigned short* aSrc = Qr + (size_t)(b * 512 + it * 128 + row_in) * NCOL + t * HH + ci_u * 8;
  const unsigned short* bSrc = Kr + (size_t)(b * 512 + jt * 128 + row_in) * NCOL + t * HH + ci_u * 8;

  f32x4 acc[4][4] = {};
  k2_loop<NCOL>(aSrc, bSrc, smem, tid, acc);

  const int lane = tid & 63, wid = tid >> 6;
  const int wr = wid >> 1, wc = wid & 1;
  const float SC = 0.125f / 12.0f;   // 64^-0.5 / 12
#pragma unroll
  for (int mf = 0; mf < 4; ++mf) {
    const int i0 = it * 128 + wr * 64 + mf * 16 + (lane >> 4) * 4;
#pragma unroll
    for (int nf = 0; nf < 4; ++nf) {
      const int j = jt * 128 + wc * 64 + nf * 16 + (lane & 15);
#pragma unroll
      for (int q = 0; q < 4; ++q) {
        size_t o = ((size_t)(b * 512 + i0 + q) * 512 + j) * 9 + t;
        out[o] = acc[mf][nf][q] * SC;
      }
    }
  }
}

// ---------------- launch ----------------

extern "C" void kernel_launch(void* const* d_in, const int* in_sizes, int n_in,
                              void* d_out, int out_size, void* d_ws, size_t ws_size,
                              hipStream_t stream) {
  const float* hs = (const float*)d_in[0];
  const float* Wq = (const float*)d_in[1];
  const float* bq = (const float*)d_in[2];
  const float* Wk = (const float*)d_in[3];
  const float* bk = (const float*)d_in[4];
  float* out = (float*)d_out;
  char* ws = (char*)d_ws;

  float2* sctab = (float2*)(ws);                               //  131072
  unsigned short* hsb = (unsigned short*)(ws + 131072);        // 6291456
  unsigned short* Wtq = (unsigned short*)(ws + 6422528);       // 10616832
  unsigned short* Wtk = (unsigned short*)(ws + 17039360);      // 10616832
  unsigned short* Qr  = (unsigned short*)(ws + 27656192);      // 56623104
  unsigned short* Kr  = (unsigned short*)(ws + 84279296);      // 56623104 -> 140902400

  hipLaunchKernelGGL(k_conv_hs, dim3(1536), dim3(256), 0, stream,
                     (const float4*)hs, (ushort8*)hsb);
  hipLaunchKernelGGL(k_transpose, dim3(216, 24, 2), dim3(32, 8), 0, stream,
                     Wq, Wk, Wtq, Wtk);
  hipLaunchKernelGGL(k_tables, dim3(64), dim3(256), 0, stream, sctab);
  hipLaunchKernelGGL(k2_rope, dim3(3456), dim3(256), 0, stream,
                     hsb, Wtq, Wtk, bq, bk, sctab, Qr, Kr);
  hipLaunchKernelGGL(k2_score, dim3(1152), dim3(256), 0, stream, Qr, Kr, out);
}